// Round 9
// baseline (139.511 us; speedup 1.0000x reference)
//
#include <hip/hip_runtime.h>
#include <math.h>

#define BB 8
#define NN 2000
#define CC 81
#define NCLS 80             // classes 1..80 (class 0 never valid)
#define MAXI 100
#define MCLS 128            // per-class member cap (mean ~25, sd ~5)
#define KCAP 2048           // emit-side key buffer (total kept <= 2000)

static constexpr float kMinConf = 0.7f;
static constexpr float kNmsThr  = 0.3f;

// ---------------- workspace layout (bytes) ----------------
// boxes   : [0,      256000)   BN*4 f32 (refined, clipped)
// sc      : [256000, 320000)   BN f32   (raw max score)
// cls     : [320000, 384000)   BN i32   (argmax class; 0 if invalid)
// kslot   : [384000, 386560)   8*80 i32  per-(batch,class) kept count
// donecnt : [386560, 386624)   8 i32 (+pad)
// klist   : [386624, 1041984)  8*80*128 u64 kept keys, fixed slots (no atomics)

// key = (score_bits << 32) | ~idx. Valid scores are positive floats so u32
// compare == float compare; key desc == (score desc, idx asc) == reference's
// stable descending argsort. idx = ~(u32)key. Keys are unique (idx).
__device__ __forceinline__ unsigned long long mkey(float s, int i) {
    return ((unsigned long long)__float_as_uint(s) << 32) | (unsigned int)(~(unsigned int)i);
}

__device__ __forceinline__ bool iou_gt_thr(float4 a, float aarea, float4 t) {
    float iy1 = fmaxf(a.x, t.x), ix1 = fmaxf(a.y, t.y);
    float iy2 = fminf(a.z, t.z), ix2 = fminf(a.w, t.w);
    float inter = fmaxf(iy2 - iy1, 0.f) * fmaxf(ix2 - ix1, 0.f);
    float tarea = (t.z - t.x) * (t.w - t.y);
    float uni = fmaxf(aarea + tarea - inter, 1e-12f);
    return inter > kNmsThr * uni;
}

// ---- kA: wave-per-ROI argmax + box refine; zero out[] and donecnt[] ----
__global__ void kA_refine(const float* __restrict__ rois,
                          const float* __restrict__ probs,
                          const float* __restrict__ deltas,
                          float* __restrict__ boxes,
                          float* __restrict__ sc,
                          int* __restrict__ cls,
                          int* __restrict__ donecnt,
                          float* __restrict__ outz) {
    int gtid = blockIdx.x * blockDim.x + threadIdx.x;
    if (gtid < BB * MAXI * 6) outz[gtid] = 0.f;      // pre-zero output
    if (gtid < BB) donecnt[gtid] = 0;

    int wid = gtid >> 6;                // one wave per ROI
    int l = gtid & 63;

    const float* p = probs + (size_t)wid * CC;
    float v1 = p[l];                    // l < 64 < 81 always valid
    int   i1 = l;
    int   c2 = l + 64;
    float v2 = (c2 < CC) ? p[c2] : -1.0f;   // probs in [0,1)
    float bv; int bi;
    if (v2 > v1) { bv = v2; bi = c2; } else { bv = v1; bi = i1; }

    #pragma unroll
    for (int off = 32; off; off >>= 1) {
        float ov = __shfl_xor(bv, off);
        int   oi = __shfl_xor(bi, off);
        if (ov > bv || (ov == bv && oi < bi)) { bv = ov; bi = oi; }
    }

    if (l == 0) {
        const float4 dl = *(const float4*)(deltas + ((size_t)wid * CC + bi) * 4);
        float dy = dl.x * 0.1f, dx = dl.y * 0.1f, dh = dl.z * 0.2f, dw = dl.w * 0.2f;
        const float4 r = *(const float4*)(rois + (size_t)wid * 4);
        float y1 = r.x, x1 = r.y, y2 = r.z, x2 = r.w;
        float h = y2 - y1, w = x2 - x1;
        float cy = y1 + 0.5f * h + dy * h;
        float cx = x1 + 0.5f * w + dx * w;
        float h2 = h * expf(dh);
        float w2 = w * expf(dw);
        float oy1 = fminf(fmaxf(cy - 0.5f * h2, 0.f), 1.f);
        float ox1 = fminf(fmaxf(cx - 0.5f * w2, 0.f), 1.f);
        float oy2 = fminf(fmaxf(cy + 0.5f * h2, 0.f), 1.f);
        float ox2 = fminf(fmaxf(cx + 0.5f * w2, 0.f), 1.f);
        bool valid = (bi > 0) && (bv >= kMinConf);
        float4 bx; bx.x = oy1; bx.y = ox1; bx.z = oy2; bx.w = ox2;
        ((float4*)boxes)[wid] = bx;
        sc[wid] = bv;
        cls[wid] = valid ? bi : 0;      // cls==0 encodes "invalid"
    }
}

// ---- kBC: one wave per (batch,class): collect -> sort -> greedy NMS ->
// fixed-slot append (no atomics). Last block per batch (done-counter) emits
// the batch's top-100 (release/acquire via __threadfence + device atomic). ----
__global__ void __launch_bounds__(64) kBC_nms_emit(
        const float* __restrict__ boxes,
        const float* __restrict__ sc,
        const int* __restrict__ cls,
        int* __restrict__ kslot,
        int* __restrict__ donecnt,
        unsigned long long* __restrict__ klist,
        float* __restrict__ out) {
    const int p = blockIdx.x;
    const int b = p / NCLS;
    const int cidx = p % NCLS;
    const int c = cidx + 1;             // classes 1..80
    const int l = threadIdx.x;

    __shared__ unsigned long long mk[MCLS];
    __shared__ float4 mbox[MCLS];

    const int* cl = cls + (size_t)b * NN;
    const float* ssc = sc + (size_t)b * NN;
    const float4* bxs = (const float4*)boxes + (size_t)b * NN;

    // ---- collect members of class c in row order (coalesced scan + ballot) --
    int cnt = 0;
    for (int ch = 0; ch < 32; ++ch) {
        int i = ch * 64 + l;
        int ci = (i < NN) ? cl[i] : 0;
        bool pred = (ci == c);
        unsigned long long mask = __ballot(pred);
        if (pred) {
            int pos = cnt + __popcll(mask & ((1ull << l) - 1ull));
            if (pos < MCLS) mk[pos] = mkey(ssc[i], i);
        }
        cnt += __popcll(mask);
    }
    if (cnt > MCLS) cnt = MCLS;

    unsigned long long kept0 = 0ull, kept1 = 0ull;
    if (cnt > 0) {
        // in-wave stable rank sort by key desc (keys unique; lockstep wave)
        {
            unsigned long long Ka = (l < cnt) ? mk[l] : 0ull;
            unsigned long long Kb = (64 + l < cnt) ? mk[64 + l] : 0ull;
            int ra = 0, rb = 0;
            for (int t = 0; t < cnt; ++t) {
                unsigned long long kt = mk[t];
                ra += (kt > Ka);
                rb += (kt > Kb);
            }
            if (l < cnt) mk[ra] = Ka;
            if (64 + l < cnt) mk[rb] = Kb;
        }
        // fetch member boxes (sorted order)
        for (int t = l; t < cnt; t += 64) {
            int i = (int)(~(unsigned int)mk[t]);
            mbox[t] = bxs[i];
        }
        // chunk 0: ballot fixpoint == greedy (validated exact)
        {
            bool act = (l < cnt);
            float4 a = mbox[act ? l : 0];
            float aarea = (a.z - a.x) * (a.w - a.y);
            unsigned long long colmask = 0ull;
            int tend = min(64, cnt);
            for (int t = 0; t < tend; ++t) {
                float4 tb = mbox[t];                  // uniform LDS broadcast
                if (t < l && act && iou_gt_thr(a, aarea, tb)) colmask |= (1ull << t);
            }
            unsigned long long kept = __ballot(act);
            while (true) {
                bool alive = act && ((colmask & kept) == 0ull);
                unsigned long long k2m = __ballot(alive);
                if (k2m == kept) break;
                kept = k2m;
            }
            kept0 = kept;
        }
        // chunk 1 (members 64..cnt-1): rare
        if (cnt > 64) {
            int m = 64 + l;
            bool act = (m < cnt);
            float4 a = mbox[act ? m : 0];
            float aarea = (a.z - a.x) * (a.w - a.y);
            bool presup = false;
            for (int t = 0; t < 64; ++t) {
                if ((kept0 >> t) & 1ull) {
                    if (act && iou_gt_thr(a, aarea, mbox[t])) presup = true;
                }
            }
            unsigned long long colmask = 0ull;
            for (int t = 64; t < cnt; ++t) {
                float4 tb = mbox[t];
                if ((t - 64) < l && act && iou_gt_thr(a, aarea, tb)) colmask |= (1ull << (t - 64));
            }
            bool pre = act && !presup;
            unsigned long long kept = __ballot(pre);
            while (true) {
                bool alive = pre && ((colmask & kept) == 0ull);
                unsigned long long k2m = __ballot(alive);
                if (k2m == kept) break;
                kept = k2m;
            }
            kept1 = kept;
        }
    }

    // ---- fixed-slot append: no atomics ----
    int nk0 = __popcll(kept0), nk1 = __popcll(kept1);
    unsigned long long* slot = klist + ((size_t)b * NCLS + cidx) * MCLS;
    if ((kept0 >> l) & 1ull)
        slot[__popcll(kept0 & ((1ull << l) - 1ull))] = mk[l];
    if (cnt > 64 && ((kept1 >> l) & 1ull))
        slot[nk0 + __popcll(kept1 & ((1ull << l) - 1ull))] = mk[64 + l];
    if (l == 0) kslot[b * NCLS + cidx] = nk0 + nk1;

    // ---- release; last block per batch proceeds to emit ----
    __threadfence();
    int done = 0;
    if (l == 0) done = atomicAdd(&donecnt[b], 1);
    done = __shfl(done, 0);
    if (done != NCLS - 1) return;
    __threadfence();                    // acquire

    // ================= emit (single wave, batch b) =================
    __shared__ unsigned long long keys[KCAP];         // 16 KB
    __shared__ unsigned long long cand[512];          //  4 KB
    __shared__ int hist[256];
    __shared__ int sbase[NCLS], scount[NCLS];

    // slot counts -> exclusive prefix (lanes 0..63 then 64..79)
    const int* ks = kslot + b * NCLS;
    int ns0 = ks[l];                                  // l in [0,64)
    int ns1 = (l < NCLS - 64) ? ks[64 + l] : 0;
    int incA = ns0, incB = ns1;
    #pragma unroll
    for (int off = 1; off < 64; off <<= 1) {
        int oa = __shfl_up(incA, off);
        int ob = __shfl_up(incB, off);
        if (l >= off) { incA += oa; incB += ob; }
    }
    int total0 = __shfl(incA, 63);
    int T = total0 + __shfl(incB, 63);
    sbase[l] = incA - ns0;
    scount[l] = ns0;
    if (l < NCLS - 64) { sbase[64 + l] = total0 + incB - ns1; scount[64 + l] = ns1; }

    // gather kept keys into contiguous LDS
    for (int s = 0; s < NCLS; ++s) {
        int ns = scount[s], base = sbase[s];
        const unsigned long long* sp = klist + ((size_t)b * NCLS + s) * MCLS;
        if (l < ns) keys[base + l] = sp[l];
        if (64 + l < ns) keys[base + 64 + l] = sp[64 + l];
    }

    // histogram on score-bucket. Kept scores in [0.7,1) -> exponent 126 fixed
    // -> top-8 mantissa bits monotone: bucket = (key >> 47) & 0xFF.
    #pragma unroll
    for (int q = 0; q < 4; ++q) hist[q * 64 + l] = 0;
    for (int t = l; t < T; t += 64)
        atomicAdd(&hist[(int)((keys[t] >> 47) & 0xFF)], 1);

    // threshold bucket tb: smallest b' with count(buckets >= b') >= 100
    int tb = 0;
    {
        int cum = 0, done2 = 0;
        for (int chunk = 3; chunk >= 0 && !done2; --chunk) {
            int bkt = chunk * 64 + (63 - l);          // lane 0 = highest bucket
            int s = hist[bkt];
            #pragma unroll
            for (int off = 1; off < 64; off <<= 1) {
                int o = __shfl_up(s, off);
                if (l >= off) s += o;
            }
            int chunktot = __shfl(s, 63);
            if (cum + chunktot >= MAXI) {
                unsigned long long m = __ballot(cum + s >= MAXI);
                int lane = __ffsll((long long)m) - 1;
                tb = chunk * 64 + (63 - lane);
                done2 = 1;
            } else {
                cum += chunktot;
            }
        }
        tb = __shfl(tb, 0) * __shfl(done2, 0);        // T<100 -> tb=0 (all)
    }

    // compact candidates (bucket >= tb); non-candidates have strictly smaller
    // keys, so rank among candidates == global rank.
    int cb = 0;
    for (int t0 = 0; t0 < T; t0 += 64) {
        int t = t0 + l;
        bool pr = (t < T) && ((int)((keys[t] >> 47) & 0xFF) >= tb);
        unsigned long long m = __ballot(pr);
        if (pr) {
            int pos = cb + __popcll(m & ((1ull << l) - 1ull));
            if (pos < 512) cand[pos] = keys[t];
        }
        cb += __popcll(m);
    }
    const unsigned long long* cset; int C;
    if (cb <= 512) { cset = cand; C = cb; }
    else           { cset = keys; C = T; }            // pathological fallback

    // exact rank-count among candidates; emit rank < 100 (out pre-zeroed)
    for (int s = l; s < C; s += 64) {
        unsigned long long myk = cset[s];
        int r = 0;
        for (int t = 0; t < C; ++t) r += (cset[t] > myk);
        if (r < MAXI) {
            int i = (int)(~(unsigned int)myk);
            float4 bx = ((const float4*)boxes)[(size_t)b * NN + i];
            float* o = out + ((size_t)b * MAXI + r) * 6;
            o[0] = bx.x; o[1] = bx.y; o[2] = bx.z; o[3] = bx.w;
            o[4] = (float)cls[(size_t)b * NN + i];
            o[5] = __uint_as_float((unsigned int)(myk >> 32));
        }
    }
}

extern "C" void kernel_launch(void* const* d_in, const int* in_sizes, int n_in,
                              void* d_out, int out_size, void* d_ws, size_t ws_size,
                              hipStream_t stream) {
    const float* rois   = (const float*)d_in[0];
    const float* probs  = (const float*)d_in[1];
    const float* deltas = (const float*)d_in[2];
    float* outp = (float*)d_out;

    char* ws = (char*)d_ws;
    float* boxes = (float*)(ws + 0);
    float* sc    = (float*)(ws + 256000);
    int*   cls   = (int*)  (ws + 320000);
    int*   kslot = (int*)  (ws + 384000);
    int*   donecnt = (int*)(ws + 386560);
    unsigned long long* klist = (unsigned long long*)(ws + 386624);

    {
        int blocks = (BB * NN * 64) / 256;   // one wave per ROI, exact
        kA_refine<<<blocks, 256, 0, stream>>>(rois, probs, deltas, boxes, sc, cls, donecnt, outp);
    }
    {
        kBC_nms_emit<<<BB * NCLS, 64, 0, stream>>>(boxes, sc, cls, kslot, donecnt, klist, outp);
    }
}

// Round 10
// 61.287 us; speedup vs baseline: 2.2763x; 2.2763x over previous
//
#include <hip/hip_runtime.h>
#include <math.h>

#define BB 8
#define NN 2000
#define CC 81
#define NCLS 80             // classes 1..80 (class 0 never valid)
#define MAXI 100
#define MCLS 128            // per-class member cap (mean ~25, sd ~5)
#define WCAP 128            // per-wave collect cap
#define KCAP 2048           // per-batch kept keys (kept <= valid <= 2000)

static constexpr float kMinConf = 0.7f;
static constexpr float kNmsThr  = 0.3f;

// ---------------- workspace layout (bytes) ----------------
// boxes : [0,      256000)   BN*4 f32 (refined, clipped)
// sc    : [256000, 320000)   BN f32   (raw max score)
// cls   : [320000, 384000)   BN i32   (argmax class; 0 if invalid)
// kslot : [384000, 386560)   8*80 i32  per-(batch,class) kept count
// klist : [386624, 1041984)  8*80*128 u64 kept keys, fixed slots (no atomics)

// key = (score_bits << 32) | ~idx. Valid scores are positive floats so u32
// compare == float compare; key desc == (score desc, idx asc) == reference's
// stable descending argsort. idx = ~(u32)key. Keys unique (idx).
__device__ __forceinline__ unsigned long long mkey(float s, int i) {
    return ((unsigned long long)__float_as_uint(s) << 32) | (unsigned int)(~(unsigned int)i);
}

__device__ __forceinline__ bool iou_gt_thr(float4 a, float aarea, float4 t) {
    float iy1 = fmaxf(a.x, t.x), ix1 = fmaxf(a.y, t.y);
    float iy2 = fminf(a.z, t.z), ix2 = fminf(a.w, t.w);
    float inter = fmaxf(iy2 - iy1, 0.f) * fmaxf(ix2 - ix1, 0.f);
    float tarea = (t.z - t.x) * (t.w - t.y);
    float uni = fmaxf(aarea + tarea - inter, 1e-12f);
    return inter > kNmsThr * uni;
}

// ---- kA: wave-per-ROI argmax + box refine; zero out[] ----
__global__ void kA_refine(const float* __restrict__ rois,
                          const float* __restrict__ probs,
                          const float* __restrict__ deltas,
                          float* __restrict__ boxes,
                          float* __restrict__ sc,
                          int* __restrict__ cls,
                          float* __restrict__ outz) {
    int gtid = blockIdx.x * blockDim.x + threadIdx.x;
    if (gtid < BB * MAXI * 6) outz[gtid] = 0.f;      // pre-zero output

    int wid = gtid >> 6;                // one wave per ROI
    int l = gtid & 63;

    const float* p = probs + (size_t)wid * CC;
    float v1 = p[l];                    // l < 64 < 81 always valid
    int   i1 = l;
    int   c2 = l + 64;
    float v2 = (c2 < CC) ? p[c2] : -1.0f;   // probs in [0,1)
    float bv; int bi;
    if (v2 > v1) { bv = v2; bi = c2; } else { bv = v1; bi = i1; }

    #pragma unroll
    for (int off = 32; off; off >>= 1) {
        float ov = __shfl_xor(bv, off);
        int   oi = __shfl_xor(bi, off);
        if (ov > bv || (ov == bv && oi < bi)) { bv = ov; bi = oi; }
    }

    if (l == 0) {
        const float4 dl = *(const float4*)(deltas + ((size_t)wid * CC + bi) * 4);
        float dy = dl.x * 0.1f, dx = dl.y * 0.1f, dh = dl.z * 0.2f, dw = dl.w * 0.2f;
        const float4 r = *(const float4*)(rois + (size_t)wid * 4);
        float y1 = r.x, x1 = r.y, y2 = r.z, x2 = r.w;
        float h = y2 - y1, w = x2 - x1;
        float cy = y1 + 0.5f * h + dy * h;
        float cx = x1 + 0.5f * w + dx * w;
        float h2 = h * expf(dh);
        float w2 = w * expf(dw);
        float oy1 = fminf(fmaxf(cy - 0.5f * h2, 0.f), 1.f);
        float ox1 = fminf(fmaxf(cx - 0.5f * w2, 0.f), 1.f);
        float oy2 = fminf(fmaxf(cy + 0.5f * h2, 0.f), 1.f);
        float ox2 = fminf(fmaxf(cx + 0.5f * w2, 0.f), 1.f);
        bool valid = (bi > 0) && (bv >= kMinConf);
        float4 bx; bx.x = oy1; bx.y = ox1; bx.z = oy2; bx.w = ox2;
        ((float4*)boxes)[wid] = bx;
        sc[wid] = bv;
        cls[wid] = valid ? bi : 0;      // cls==0 encodes "invalid"
    }
}

// ---- kB: one 256-thread block per (batch,class). 4 waves scan 500-row
// quarters in parallel (latency hiding), merge member lists via LDS prefix;
// wave 0 runs the proven sort + ballot-fixpoint greedy NMS; kept keys go to
// a fixed per-class slot. NO global atomics, NO fences. ----
__global__ void __launch_bounds__(256) kB_nms(
        const float* __restrict__ boxes,
        const float* __restrict__ sc,
        const int* __restrict__ cls,
        int* __restrict__ kslot,
        unsigned long long* __restrict__ klist) {
    const int p = blockIdx.x;
    const int b = p / NCLS;
    const int cidx = p % NCLS;
    const int c = cidx + 1;             // classes 1..80
    const int tid = threadIdx.x;
    const int wv = tid >> 6;
    const int l = tid & 63;

    __shared__ unsigned long long wlist[4][WCAP];   // 4 KB
    __shared__ int wcnt[4];
    __shared__ unsigned long long mk[MCLS];         // 1 KB
    __shared__ float4 mbox[MCLS];                   // 2 KB

    const int* cl = cls + (size_t)b * NN;
    const float* ssc = sc + (size_t)b * NN;
    const float4* bxs = (const float4*)boxes + (size_t)b * NN;

    // ---- parallel collect: wave wv scans rows [wv*500, wv*500+500) ----
    {
        int cnt = 0;
        const int base_row = wv * 500;
        for (int ch = 0; ch < 8; ++ch) {
            int idx = ch * 64 + l;                   // 0..511
            bool inq = idx < 500;
            int r = base_row + idx;
            int ci = inq ? cl[r] : 0;
            bool pred = (ci == c);
            unsigned long long mask = __ballot(pred);
            if (pred) {
                int pos = cnt + __popcll(mask & ((1ull << l) - 1ull));
                if (pos < WCAP) wlist[wv][pos] = mkey(ssc[r], r);
            }
            cnt += __popcll(mask);
        }
        if (l == 0) wcnt[wv] = (cnt > WCAP) ? WCAP : cnt;
    }
    __syncthreads();

    // merge wave lists into mk (order irrelevant; sort is total on unique keys)
    int b0 = wcnt[0], b1 = wcnt[1], b2 = wcnt[2], b3 = wcnt[3];
    int myofs = (wv > 0 ? b0 : 0) + (wv > 1 ? b1 : 0) + (wv > 2 ? b2 : 0);
    int myn = wcnt[wv];
    int cnt_all = b0 + b1 + b2 + b3;
    if (cnt_all > MCLS) cnt_all = MCLS;
    if (l < myn && myofs + l < MCLS) mk[myofs + l] = wlist[wv][l];
    if (64 + l < myn && myofs + 64 + l < MCLS) mk[myofs + 64 + l] = wlist[wv][64 + l];
    __syncthreads();

    if (wv != 0) return;                             // no further barriers
    if (cnt_all == 0) {
        if (l == 0) kslot[b * NCLS + cidx] = 0;
        return;
    }
    const int cnt = cnt_all;

    // ---- in-wave stable rank sort by key desc (two keys per lane) ----
    {
        unsigned long long Ka = (l < cnt) ? mk[l] : 0ull;
        unsigned long long Kb = (64 + l < cnt) ? mk[64 + l] : 0ull;
        int ra = 0, rb = 0;
        for (int t = 0; t < cnt; ++t) {
            unsigned long long kt = mk[t];           // uniform LDS broadcast
            ra += (kt > Ka);
            rb += (kt > Kb);
        }
        if (l < cnt) mk[ra] = Ka;
        if (64 + l < cnt) mk[rb] = Kb;
    }

    // fetch member boxes (sorted order)
    for (int t = l; t < cnt; t += 64) {
        int i = (int)(~(unsigned int)mk[t]);
        mbox[t] = bxs[i];
    }

    // ---- chunk 0: ballot fixpoint == greedy (validated exact) ----
    unsigned long long kept0 = 0ull, kept1 = 0ull;
    {
        bool act = (l < cnt);
        float4 a = mbox[act ? l : 0];
        float aarea = (a.z - a.x) * (a.w - a.y);
        unsigned long long colmask = 0ull;
        int tend = min(64, cnt);
        for (int t = 0; t < tend; ++t) {
            float4 tb = mbox[t];                     // uniform LDS broadcast
            if (t < l && act && iou_gt_thr(a, aarea, tb)) colmask |= (1ull << t);
        }
        unsigned long long kept = __ballot(act);
        while (true) {
            bool alive = act && ((colmask & kept) == 0ull);
            unsigned long long k2m = __ballot(alive);
            if (k2m == kept) break;
            kept = k2m;
        }
        kept0 = kept;
    }
    // ---- chunk 1 (members 64..cnt-1): rare ----
    if (cnt > 64) {
        int m = 64 + l;
        bool act = (m < cnt);
        float4 a = mbox[act ? m : 0];
        float aarea = (a.z - a.x) * (a.w - a.y);
        bool presup = false;
        for (int t = 0; t < 64; ++t) {
            if ((kept0 >> t) & 1ull) {
                if (act && iou_gt_thr(a, aarea, mbox[t])) presup = true;
            }
        }
        unsigned long long colmask = 0ull;
        for (int t = 64; t < cnt; ++t) {
            float4 tb = mbox[t];
            if ((t - 64) < l && act && iou_gt_thr(a, aarea, tb)) colmask |= (1ull << (t - 64));
        }
        bool pre = act && !presup;
        unsigned long long kept = __ballot(pre);
        while (true) {
            bool alive = pre && ((colmask & kept) == 0ull);
            unsigned long long k2m = __ballot(alive);
            if (k2m == kept) break;
            kept = k2m;
        }
        kept1 = kept;
    }

    // ---- fixed-slot write (disjoint per block; kernel boundary = sync) ----
    int nk0 = __popcll(kept0), nk1 = __popcll(kept1);
    unsigned long long* slot = klist + ((size_t)b * NCLS + cidx) * MCLS;
    if ((kept0 >> l) & 1ull)
        slot[__popcll(kept0 & ((1ull << l) - 1ull))] = mk[l];
    if (cnt > 64 && ((kept1 >> l) & 1ull))
        slot[nk0 + __popcll(kept1 & ((1ull << l) - 1ull))] = mk[64 + l];
    if (l == 0) kslot[b * NCLS + cidx] = nk0 + nk1;
}

// ---- kC: per-batch emit: slot prefix -> gather -> histogram threshold ->
// candidate rank-count -> write top-100 ----
__global__ void __launch_bounds__(256) kC_emit(
        const int* __restrict__ kslot,
        const unsigned long long* __restrict__ klist,
        const float* __restrict__ boxes,
        const int* __restrict__ cls,
        float* __restrict__ out) {
    const int b = blockIdx.x;
    const int tid = threadIdx.x;
    const int wv = tid >> 6;
    const int l = tid & 63;

    __shared__ unsigned long long keys[KCAP];        // 16 KB
    __shared__ unsigned long long cand[512];         //  4 KB
    __shared__ int hist[256];
    __shared__ int sbase[NCLS], scount[NCLS];
    __shared__ int Tsh, tbsh, candn;

    hist[tid] = 0;
    if (tid == 0) candn = 0;

    // wave 0: 80 slot counts -> exclusive prefix
    if (wv == 0) {
        const int* ks = kslot + b * NCLS;
        int ns0 = ks[l];
        int ns1 = (l < NCLS - 64) ? ks[64 + l] : 0;
        int incA = ns0, incB = ns1;
        #pragma unroll
        for (int off = 1; off < 64; off <<= 1) {
            int oa = __shfl_up(incA, off);
            int ob = __shfl_up(incB, off);
            if (l >= off) { incA += oa; incB += ob; }
        }
        int total0 = __shfl(incA, 63);
        int T = total0 + __shfl(incB, 63);
        sbase[l] = incA - ns0;
        scount[l] = ns0;
        if (l < NCLS - 64) { sbase[64 + l] = total0 + incB - ns1; scount[64 + l] = ns1; }
        if (l == 0) Tsh = (T > KCAP) ? KCAP : T;
    }
    __syncthreads();
    const int T = Tsh;
    if (T == 0) return;                              // uniform; out pre-zeroed

    // gather: wave wv handles slots wv*20 .. wv*20+19
    for (int s = wv * 20; s < wv * 20 + 20; ++s) {
        int ns = scount[s], base = sbase[s];
        const unsigned long long* sp = klist + ((size_t)b * NCLS + s) * MCLS;
        if (l < ns) keys[base + l] = sp[l];
        if (64 + l < ns) keys[base + 64 + l] = sp[64 + l];
    }
    __syncthreads();

    // histogram on score bucket. Kept scores in [0.7,1) -> exponent 126 fixed
    // -> top-8 mantissa bits monotone: bucket = (key >> 47) & 0xFF.
    for (int t = tid; t < T; t += 256)
        atomicAdd(&hist[(int)((keys[t] >> 47) & 0xFF)], 1);
    __syncthreads();

    // wave 0: threshold bucket tb (smallest b' with count(buckets >= b') >= 100)
    if (wv == 0) {
        int cum = 0, tb = 0, done = 0;
        for (int chunk = 3; chunk >= 0 && !done; --chunk) {
            int bkt = chunk * 64 + (63 - l);         // lane 0 = highest bucket
            int s = hist[bkt];
            #pragma unroll
            for (int off = 1; off < 64; off <<= 1) {
                int o = __shfl_up(s, off);
                if (l >= off) s += o;
            }
            int chunktot = __shfl(s, 63);
            if (cum + chunktot >= MAXI) {
                unsigned long long m = __ballot(cum + s >= MAXI);
                int lane = __ffsll((long long)m) - 1;
                tb = chunk * 64 + (63 - lane);
                done = 1;
            } else {
                cum += chunktot;
            }
        }
        if (l == 0) tbsh = done ? tb : 0;            // T<100 -> all buckets
    }
    __syncthreads();
    const int tb = tbsh;

    // compact candidates (bucket >= tb); non-candidates have strictly smaller
    // keys, so rank among candidates == global rank.
    for (int t = tid; t < ((T + 255) & ~255); t += 256) {
        bool pr = (t < T) && ((int)((keys[t] >> 47) & 0xFF) >= tb);
        unsigned long long m = __ballot(pr);
        int nb = __popcll(m);
        int basew = 0;
        if (l == 0 && nb) basew = atomicAdd(&candn, nb);
        basew = __shfl(basew, 0);
        if (pr) {
            int pos = basew + __popcll(m & ((1ull << l) - 1ull));
            if (pos < 512) cand[pos] = keys[t];
        }
    }
    __syncthreads();
    int nc = candn;
    const unsigned long long* cset; int C;
    if (nc <= 512) { cset = cand; C = nc; }
    else           { cset = keys; C = T; }           // pathological fallback

    // exact rank-count among candidates; emit rank < 100 (out pre-zeroed)
    for (int s = tid; s < C; s += 256) {
        unsigned long long myk = cset[s];
        int r = 0;
        for (int t = 0; t < C; ++t) r += (cset[t] > myk);
        if (r < MAXI) {
            int i = (int)(~(unsigned int)myk);
            float4 bx = ((const float4*)boxes)[(size_t)b * NN + i];
            float* o = out + ((size_t)b * MAXI + r) * 6;
            o[0] = bx.x; o[1] = bx.y; o[2] = bx.z; o[3] = bx.w;
            o[4] = (float)cls[(size_t)b * NN + i];
            o[5] = __uint_as_float((unsigned int)(myk >> 32));
        }
    }
}

extern "C" void kernel_launch(void* const* d_in, const int* in_sizes, int n_in,
                              void* d_out, int out_size, void* d_ws, size_t ws_size,
                              hipStream_t stream) {
    const float* rois   = (const float*)d_in[0];
    const float* probs  = (const float*)d_in[1];
    const float* deltas = (const float*)d_in[2];
    float* outp = (float*)d_out;

    char* ws = (char*)d_ws;
    float* boxes = (float*)(ws + 0);
    float* sc    = (float*)(ws + 256000);
    int*   cls   = (int*)  (ws + 320000);
    int*   kslot = (int*)  (ws + 384000);
    unsigned long long* klist = (unsigned long long*)(ws + 386624);

    {
        int blocks = (BB * NN * 64) / 256;   // one wave per ROI, exact
        kA_refine<<<blocks, 256, 0, stream>>>(rois, probs, deltas, boxes, sc, cls, outp);
    }
    {
        kB_nms<<<BB * NCLS, 256, 0, stream>>>(boxes, sc, cls, kslot, klist);
    }
    {
        kC_emit<<<BB, 256, 0, stream>>>(kslot, klist, boxes, cls, outp);
    }
}

// Round 11
// 47.355 us; speedup vs baseline: 2.9461x; 1.2942x over previous
//
#include <hip/hip_runtime.h>
#include <math.h>

#define BB 8
#define NN 2000
#define CC 81
#define NCLS 80             // classes 1..80 (class 0 never valid)
#define MAXI 100
#define MCLS 128            // per-class member cap (mean ~25, sd ~5)
#define WCAP 128            // per-wave collect cap
#define KCAP 2048           // per-batch kept keys (kept <= valid <= 2000)

static constexpr float kMinConf = 0.7f;
static constexpr float kNmsThr  = 0.3f;

// ---------------- workspace layout (bytes) ----------------
// boxes : [0,      256000)   BN*4 f32 (refined, clipped)
// sc    : [256000, 320000)   BN f32   (raw max score)
// cls   : [320000, 384000)   BN i32   (argmax class; 0 if invalid)
// kslot : [384000, 386560)   8*80 i32  per-(batch,class) kept count
// klist : [386624, 1041984)  8*80*128 u64 kept keys, fixed slots (no atomics)

// key = (score_bits << 32) | ~idx. Valid scores are positive floats so u32
// compare == float compare; key desc == (score desc, idx asc) == reference's
// stable descending argsort. idx = ~(u32)key. Keys unique (idx).
__device__ __forceinline__ unsigned long long mkey(float s, int i) {
    return ((unsigned long long)__float_as_uint(s) << 32) | (unsigned int)(~(unsigned int)i);
}

__device__ __forceinline__ bool iou_gt_thr(float4 a, float aarea, float4 t) {
    float iy1 = fmaxf(a.x, t.x), ix1 = fmaxf(a.y, t.y);
    float iy2 = fminf(a.z, t.z), ix2 = fminf(a.w, t.w);
    float inter = fmaxf(iy2 - iy1, 0.f) * fmaxf(ix2 - ix1, 0.f);
    float tarea = (t.z - t.x) * (t.w - t.y);
    float uni = fmaxf(aarea + tarea - inter, 1e-12f);
    return inter > kNmsThr * uni;
}

// ---- kA: wave-per-ROI argmax + box refine; zero out[] ----
__global__ void kA_refine(const float* __restrict__ rois,
                          const float* __restrict__ probs,
                          const float* __restrict__ deltas,
                          float* __restrict__ boxes,
                          float* __restrict__ sc,
                          int* __restrict__ cls,
                          float* __restrict__ outz) {
    int gtid = blockIdx.x * blockDim.x + threadIdx.x;
    if (gtid < BB * MAXI * 6) outz[gtid] = 0.f;      // pre-zero output

    int wid = gtid >> 6;                // one wave per ROI
    int l = gtid & 63;

    const float* p = probs + (size_t)wid * CC;
    float v1 = p[l];                    // l < 64 < 81 always valid
    int   i1 = l;
    int   c2 = l + 64;
    float v2 = (c2 < CC) ? p[c2] : -1.0f;   // probs in [0,1)
    float bv; int bi;
    if (v2 > v1) { bv = v2; bi = c2; } else { bv = v1; bi = i1; }

    #pragma unroll
    for (int off = 32; off; off >>= 1) {
        float ov = __shfl_xor(bv, off);
        int   oi = __shfl_xor(bi, off);
        if (ov > bv || (ov == bv && oi < bi)) { bv = ov; bi = oi; }
    }

    if (l == 0) {
        const float4 dl = *(const float4*)(deltas + ((size_t)wid * CC + bi) * 4);
        float dy = dl.x * 0.1f, dx = dl.y * 0.1f, dh = dl.z * 0.2f, dw = dl.w * 0.2f;
        const float4 r = *(const float4*)(rois + (size_t)wid * 4);
        float y1 = r.x, x1 = r.y, y2 = r.z, x2 = r.w;
        float h = y2 - y1, w = x2 - x1;
        float cy = y1 + 0.5f * h + dy * h;
        float cx = x1 + 0.5f * w + dx * w;
        float h2 = h * expf(dh);
        float w2 = w * expf(dw);
        float oy1 = fminf(fmaxf(cy - 0.5f * h2, 0.f), 1.f);
        float ox1 = fminf(fmaxf(cx - 0.5f * w2, 0.f), 1.f);
        float oy2 = fminf(fmaxf(cy + 0.5f * h2, 0.f), 1.f);
        float ox2 = fminf(fmaxf(cx + 0.5f * w2, 0.f), 1.f);
        bool valid = (bi > 0) && (bv >= kMinConf);
        float4 bx; bx.x = oy1; bx.y = ox1; bx.z = oy2; bx.w = ox2;
        ((float4*)boxes)[wid] = bx;
        sc[wid] = bv;
        cls[wid] = valid ? bi : 0;      // cls==0 encodes "invalid"
    }
}

// ---- kB: one 256-thread block per (batch,class). 4 waves scan 500-row
// quarters in parallel, merge member lists via LDS prefix; wave 0 runs the
// proven sort + ballot-fixpoint greedy NMS; kept keys go to a fixed per-class
// slot. NO global atomics, NO fences. ----
__global__ void __launch_bounds__(256) kB_nms(
        const float* __restrict__ boxes,
        const float* __restrict__ sc,
        const int* __restrict__ cls,
        int* __restrict__ kslot,
        unsigned long long* __restrict__ klist) {
    const int p = blockIdx.x;
    const int b = p / NCLS;
    const int cidx = p % NCLS;
    const int c = cidx + 1;             // classes 1..80
    const int tid = threadIdx.x;
    const int wv = tid >> 6;
    const int l = tid & 63;

    __shared__ unsigned long long wlist[4][WCAP];   // 4 KB
    __shared__ int wcnt[4];
    __shared__ unsigned long long mk[MCLS];         // 1 KB
    __shared__ float4 mbox[MCLS];                   // 2 KB

    const int* cl = cls + (size_t)b * NN;
    const float* ssc = sc + (size_t)b * NN;
    const float4* bxs = (const float4*)boxes + (size_t)b * NN;

    // ---- parallel collect: wave wv scans rows [wv*500, wv*500+500) ----
    {
        int cnt = 0;
        const int base_row = wv * 500;
        for (int ch = 0; ch < 8; ++ch) {
            int idx = ch * 64 + l;                   // 0..511
            bool inq = idx < 500;
            int r = base_row + idx;
            int ci = inq ? cl[r] : 0;
            bool pred = (ci == c);
            unsigned long long mask = __ballot(pred);
            if (pred) {
                int pos = cnt + __popcll(mask & ((1ull << l) - 1ull));
                if (pos < WCAP) wlist[wv][pos] = mkey(ssc[r], r);
            }
            cnt += __popcll(mask);
        }
        if (l == 0) wcnt[wv] = (cnt > WCAP) ? WCAP : cnt;
    }
    __syncthreads();

    // merge wave lists into mk (order irrelevant; sort is total on unique keys)
    int b0 = wcnt[0], b1 = wcnt[1], b2 = wcnt[2], b3 = wcnt[3];
    int myofs = (wv > 0 ? b0 : 0) + (wv > 1 ? b1 : 0) + (wv > 2 ? b2 : 0);
    int myn = wcnt[wv];
    int cnt_all = b0 + b1 + b2 + b3;
    if (cnt_all > MCLS) cnt_all = MCLS;
    if (l < myn && myofs + l < MCLS) mk[myofs + l] = wlist[wv][l];
    if (64 + l < myn && myofs + 64 + l < MCLS) mk[myofs + 64 + l] = wlist[wv][64 + l];
    __syncthreads();

    if (wv != 0) return;                             // no further barriers
    if (cnt_all == 0) {
        if (l == 0) kslot[b * NCLS + cidx] = 0;
        return;
    }
    const int cnt = cnt_all;

    // ---- in-wave stable rank sort by key desc (two keys per lane) ----
    {
        unsigned long long Ka = (l < cnt) ? mk[l] : 0ull;
        unsigned long long Kb = (64 + l < cnt) ? mk[64 + l] : 0ull;
        int ra = 0, rb = 0;
        for (int t = 0; t < cnt; ++t) {
            unsigned long long kt = mk[t];           // uniform LDS broadcast
            ra += (kt > Ka);
            rb += (kt > Kb);
        }
        if (l < cnt) mk[ra] = Ka;
        if (64 + l < cnt) mk[rb] = Kb;
    }

    // fetch member boxes (sorted order)
    for (int t = l; t < cnt; t += 64) {
        int i = (int)(~(unsigned int)mk[t]);
        mbox[t] = bxs[i];
    }

    // ---- chunk 0: ballot fixpoint == greedy (validated exact) ----
    unsigned long long kept0 = 0ull, kept1 = 0ull;
    {
        bool act = (l < cnt);
        float4 a = mbox[act ? l : 0];
        float aarea = (a.z - a.x) * (a.w - a.y);
        unsigned long long colmask = 0ull;
        int tend = min(64, cnt);
        for (int t = 0; t < tend; ++t) {
            float4 tb = mbox[t];                     // uniform LDS broadcast
            if (t < l && act && iou_gt_thr(a, aarea, tb)) colmask |= (1ull << t);
        }
        unsigned long long kept = __ballot(act);
        while (true) {
            bool alive = act && ((colmask & kept) == 0ull);
            unsigned long long k2m = __ballot(alive);
            if (k2m == kept) break;
            kept = k2m;
        }
        kept0 = kept;
    }
    // ---- chunk 1 (members 64..cnt-1): rare ----
    if (cnt > 64) {
        int m = 64 + l;
        bool act = (m < cnt);
        float4 a = mbox[act ? m : 0];
        float aarea = (a.z - a.x) * (a.w - a.y);
        bool presup = false;
        for (int t = 0; t < 64; ++t) {
            if ((kept0 >> t) & 1ull) {
                if (act && iou_gt_thr(a, aarea, mbox[t])) presup = true;
            }
        }
        unsigned long long colmask = 0ull;
        for (int t = 64; t < cnt; ++t) {
            float4 tb = mbox[t];
            if ((t - 64) < l && act && iou_gt_thr(a, aarea, tb)) colmask |= (1ull << (t - 64));
        }
        bool pre = act && !presup;
        unsigned long long kept = __ballot(pre);
        while (true) {
            bool alive = pre && ((colmask & kept) == 0ull);
            unsigned long long k2m = __ballot(alive);
            if (k2m == kept) break;
            kept = k2m;
        }
        kept1 = kept;
    }

    // ---- fixed-slot write (disjoint per block; kernel boundary = sync) ----
    int nk0 = __popcll(kept0), nk1 = __popcll(kept1);
    unsigned long long* slot = klist + ((size_t)b * NCLS + cidx) * MCLS;
    if ((kept0 >> l) & 1ull)
        slot[__popcll(kept0 & ((1ull << l) - 1ull))] = mk[l];
    if (cnt > 64 && ((kept1 >> l) & 1ull))
        slot[nk0 + __popcll(kept1 & ((1ull << l) - 1ull))] = mk[64 + l];
    if (l == 0) kslot[b * NCLS + cidx] = nk0 + nk1;
}

// ---- kC: 4 blocks per batch x 512 threads. Stage ALL slot entries with
// unconditional coalesced loads + predicated LDS scatter (no serial per-slot
// loop); rank-count a 512-key slice against all T keys (ulonglong2 LDS reads,
// bounded, no data-dependent fallback); write rank<100 rows. ----
__global__ void __launch_bounds__(512) kC_emit(
        const int* __restrict__ kslot,
        const unsigned long long* __restrict__ klist,
        const float* __restrict__ boxes,
        const int* __restrict__ cls,
        float* __restrict__ out) {
    const int b = blockIdx.x >> 2;
    const int q = blockIdx.x & 3;
    const int tid = threadIdx.x;
    const int wv = tid >> 6;
    const int l = tid & 63;

    __shared__ ulonglong2 keys2[KCAP / 2];           // 16 KB
    __shared__ int sbase[NCLS], scount[NCLS];
    __shared__ int Tsh;
    unsigned long long* keys = (unsigned long long*)keys2;

    // wave 0: 80 slot counts -> exclusive prefix (validated)
    if (wv == 0) {
        const int* ks = kslot + b * NCLS;
        int ns0 = ks[l];
        int ns1 = (l < NCLS - 64) ? ks[64 + l] : 0;
        int incA = ns0, incB = ns1;
        #pragma unroll
        for (int off = 1; off < 64; off <<= 1) {
            int oa = __shfl_up(incA, off);
            int ob = __shfl_up(incB, off);
            if (l >= off) { incA += oa; incB += ob; }
        }
        int total0 = __shfl(incA, 63);
        int T = total0 + __shfl(incB, 63);
        sbase[l] = incA - ns0;
        scount[l] = ns0;
        if (l < NCLS - 64) { sbase[64 + l] = total0 + incB - ns1; scount[64 + l] = ns1; }
        if (l == 0) Tsh = T;                          // T <= 2000
    }
    __syncthreads();
    const int T = Tsh;

    // stage: all 80*128 entries, coalesced unconditional loads, predicated scatter
    const unsigned long long* kbase = klist + (size_t)b * NCLS * MCLS;
    for (int e = tid; e < NCLS * MCLS; e += 512) {
        unsigned long long v = kbase[e];
        int s = e >> 7, j = e & (MCLS - 1);
        if (j < scount[s]) keys[sbase[s] + j] = v;
    }
    if (tid == 0) keys[T] = 0ull;                     // pad for odd-T pair read
    __syncthreads();

    // rank-count slice [q*512, q*512+512)
    const int k = q * 512 + tid;
    if (k < T) {
        unsigned long long myk = keys[k];
        int r = 0;
        const int np = (T + 1) >> 1;
        for (int t = 0; t < np; ++t) {
            ulonglong2 kv = keys2[t];
            r += (int)(kv.x > myk);
            r += (int)(kv.y > myk);                   // keys[T]=0 never counts
        }
        if (r < MAXI) {
            int i = (int)(~(unsigned int)myk);
            float4 bx = ((const float4*)boxes)[(size_t)b * NN + i];
            float* o = out + ((size_t)b * MAXI + r) * 6;
            o[0] = bx.x; o[1] = bx.y; o[2] = bx.z; o[3] = bx.w;
            o[4] = (float)cls[(size_t)b * NN + i];
            o[5] = __uint_as_float((unsigned int)(myk >> 32));
        }
    }
}

extern "C" void kernel_launch(void* const* d_in, const int* in_sizes, int n_in,
                              void* d_out, int out_size, void* d_ws, size_t ws_size,
                              hipStream_t stream) {
    const float* rois   = (const float*)d_in[0];
    const float* probs  = (const float*)d_in[1];
    const float* deltas = (const float*)d_in[2];
    float* outp = (float*)d_out;

    char* ws = (char*)d_ws;
    float* boxes = (float*)(ws + 0);
    float* sc    = (float*)(ws + 256000);
    int*   cls   = (int*)  (ws + 320000);
    int*   kslot = (int*)  (ws + 384000);
    unsigned long long* klist = (unsigned long long*)(ws + 386624);

    {
        int blocks = (BB * NN * 64) / 256;   // one wave per ROI, exact
        kA_refine<<<blocks, 256, 0, stream>>>(rois, probs, deltas, boxes, sc, cls, outp);
    }
    {
        kB_nms<<<BB * NCLS, 256, 0, stream>>>(boxes, sc, cls, kslot, klist);
    }
    {
        kC_emit<<<BB * 4, 512, 0, stream>>>(kslot, klist, boxes, cls, outp);
    }
}

// Round 12
// 35.371 us; speedup vs baseline: 3.9442x; 1.3388x over previous
//
#include <hip/hip_runtime.h>
#include <math.h>

#define BB 8
#define NN 2000
#define CC 81
#define NCLS 80             // classes 1..80 (class 0 never valid)
#define MAXI 100
#define MCLS 128            // per-class member cap (mean ~25, sd ~5)
#define WCAP 128            // per-wave collect cap
#define KCAP 2048           // per-batch kept keys (kept <= valid <= 2000)

static constexpr float kMinConf = 0.7f;
static constexpr float kNmsThr  = 0.3f;

// ---------------- workspace layout (bytes) ----------------
// boxes : [0,      256000)   BN*4 f32 (refined, clipped)
// sc    : [256000, 320000)   BN f32   (raw max score)
// cls   : [320000, 384000)   BN i32   (argmax class; 0 if invalid)
// kslot : [384000, 386560)   8*80 i32  per-(batch,class) kept count
// klist : [386624, 1041984)  8*80*128 u64 kept keys, fixed slots (no atomics)

// key = (score_bits << 32) | ~idx. Valid scores are positive floats so u32
// compare == float compare; key desc == (score desc, idx asc) == reference's
// stable descending argsort. idx = ~(u32)key. Keys unique (idx).
__device__ __forceinline__ unsigned long long mkey(float s, int i) {
    return ((unsigned long long)__float_as_uint(s) << 32) | (unsigned int)(~(unsigned int)i);
}

__device__ __forceinline__ bool iou_gt_thr(float4 a, float aarea, float4 t) {
    float iy1 = fmaxf(a.x, t.x), ix1 = fmaxf(a.y, t.y);
    float iy2 = fminf(a.z, t.z), ix2 = fminf(a.w, t.w);
    float inter = fmaxf(iy2 - iy1, 0.f) * fmaxf(ix2 - ix1, 0.f);
    float tarea = (t.z - t.x) * (t.w - t.y);
    float uni = fmaxf(aarea + tarea - inter, 1e-12f);
    return inter > kNmsThr * uni;
}

// ---- kA: wave-per-ROI argmax + box refine; zero out[] ----
__global__ void kA_refine(const float* __restrict__ rois,
                          const float* __restrict__ probs,
                          const float* __restrict__ deltas,
                          float* __restrict__ boxes,
                          float* __restrict__ sc,
                          int* __restrict__ cls,
                          float* __restrict__ outz) {
    int gtid = blockIdx.x * blockDim.x + threadIdx.x;
    if (gtid < BB * MAXI * 6) outz[gtid] = 0.f;      // pre-zero output

    int wid = gtid >> 6;                // one wave per ROI
    int l = gtid & 63;

    const float* p = probs + (size_t)wid * CC;
    float v1 = p[l];                    // l < 64 < 81 always valid
    int   i1 = l;
    int   c2 = l + 64;
    float v2 = (c2 < CC) ? p[c2] : -1.0f;   // probs in [0,1)
    float bv; int bi;
    if (v2 > v1) { bv = v2; bi = c2; } else { bv = v1; bi = i1; }

    #pragma unroll
    for (int off = 32; off; off >>= 1) {
        float ov = __shfl_xor(bv, off);
        int   oi = __shfl_xor(bi, off);
        if (ov > bv || (ov == bv && oi < bi)) { bv = ov; bi = oi; }
    }

    if (l == 0) {
        const float4 dl = *(const float4*)(deltas + ((size_t)wid * CC + bi) * 4);
        float dy = dl.x * 0.1f, dx = dl.y * 0.1f, dh = dl.z * 0.2f, dw = dl.w * 0.2f;
        const float4 r = *(const float4*)(rois + (size_t)wid * 4);
        float y1 = r.x, x1 = r.y, y2 = r.z, x2 = r.w;
        float h = y2 - y1, w = x2 - x1;
        float cy = y1 + 0.5f * h + dy * h;
        float cx = x1 + 0.5f * w + dx * w;
        float h2 = h * expf(dh);
        float w2 = w * expf(dw);
        float oy1 = fminf(fmaxf(cy - 0.5f * h2, 0.f), 1.f);
        float ox1 = fminf(fmaxf(cx - 0.5f * w2, 0.f), 1.f);
        float oy2 = fminf(fmaxf(cy + 0.5f * h2, 0.f), 1.f);
        float ox2 = fminf(fmaxf(cx + 0.5f * w2, 0.f), 1.f);
        bool valid = (bi > 0) && (bv >= kMinConf);
        float4 bx; bx.x = oy1; bx.y = ox1; bx.z = oy2; bx.w = ox2;
        ((float4*)boxes)[wid] = bx;
        sc[wid] = bv;
        cls[wid] = valid ? bi : 0;      // cls==0 encodes "invalid"
    }
}

// ---- kB: one 256-thread block per (batch,class). 4 waves scan 500-row
// quarters in parallel, merge member lists via LDS prefix; wave 0 runs the
// proven sort + ballot-fixpoint greedy NMS; kept keys go to a fixed per-class
// slot. NO global atomics, NO fences. (R11-validated, unchanged) ----
__global__ void __launch_bounds__(256) kB_nms(
        const float* __restrict__ boxes,
        const float* __restrict__ sc,
        const int* __restrict__ cls,
        int* __restrict__ kslot,
        unsigned long long* __restrict__ klist) {
    const int p = blockIdx.x;
    const int b = p / NCLS;
    const int cidx = p % NCLS;
    const int c = cidx + 1;             // classes 1..80
    const int tid = threadIdx.x;
    const int wv = tid >> 6;
    const int l = tid & 63;

    __shared__ unsigned long long wlist[4][WCAP];   // 4 KB
    __shared__ int wcnt[4];
    __shared__ unsigned long long mk[MCLS];         // 1 KB
    __shared__ float4 mbox[MCLS];                   // 2 KB

    const int* cl = cls + (size_t)b * NN;
    const float* ssc = sc + (size_t)b * NN;
    const float4* bxs = (const float4*)boxes + (size_t)b * NN;

    // ---- parallel collect: wave wv scans rows [wv*500, wv*500+500) ----
    {
        int cnt = 0;
        const int base_row = wv * 500;
        for (int ch = 0; ch < 8; ++ch) {
            int idx = ch * 64 + l;                   // 0..511
            bool inq = idx < 500;
            int r = base_row + idx;
            int ci = inq ? cl[r] : 0;
            bool pred = (ci == c);
            unsigned long long mask = __ballot(pred);
            if (pred) {
                int pos = cnt + __popcll(mask & ((1ull << l) - 1ull));
                if (pos < WCAP) wlist[wv][pos] = mkey(ssc[r], r);
            }
            cnt += __popcll(mask);
        }
        if (l == 0) wcnt[wv] = (cnt > WCAP) ? WCAP : cnt;
    }
    __syncthreads();

    // merge wave lists into mk (order irrelevant; sort is total on unique keys)
    int b0 = wcnt[0], b1 = wcnt[1], b2 = wcnt[2], b3 = wcnt[3];
    int myofs = (wv > 0 ? b0 : 0) + (wv > 1 ? b1 : 0) + (wv > 2 ? b2 : 0);
    int myn = wcnt[wv];
    int cnt_all = b0 + b1 + b2 + b3;
    if (cnt_all > MCLS) cnt_all = MCLS;
    if (l < myn && myofs + l < MCLS) mk[myofs + l] = wlist[wv][l];
    if (64 + l < myn && myofs + 64 + l < MCLS) mk[myofs + 64 + l] = wlist[wv][64 + l];
    __syncthreads();

    if (wv != 0) return;                             // no further barriers
    if (cnt_all == 0) {
        if (l == 0) kslot[b * NCLS + cidx] = 0;
        return;
    }
    const int cnt = cnt_all;

    // ---- in-wave stable rank sort by key desc (two keys per lane) ----
    {
        unsigned long long Ka = (l < cnt) ? mk[l] : 0ull;
        unsigned long long Kb = (64 + l < cnt) ? mk[64 + l] : 0ull;
        int ra = 0, rb = 0;
        for (int t = 0; t < cnt; ++t) {
            unsigned long long kt = mk[t];           // uniform LDS broadcast
            ra += (kt > Ka);
            rb += (kt > Kb);
        }
        if (l < cnt) mk[ra] = Ka;
        if (64 + l < cnt) mk[rb] = Kb;
    }

    // fetch member boxes (sorted order)
    for (int t = l; t < cnt; t += 64) {
        int i = (int)(~(unsigned int)mk[t]);
        mbox[t] = bxs[i];
    }

    // ---- chunk 0: ballot fixpoint == greedy (validated exact) ----
    unsigned long long kept0 = 0ull, kept1 = 0ull;
    {
        bool act = (l < cnt);
        float4 a = mbox[act ? l : 0];
        float aarea = (a.z - a.x) * (a.w - a.y);
        unsigned long long colmask = 0ull;
        int tend = min(64, cnt);
        for (int t = 0; t < tend; ++t) {
            float4 tb = mbox[t];                     // uniform LDS broadcast
            if (t < l && act && iou_gt_thr(a, aarea, tb)) colmask |= (1ull << t);
        }
        unsigned long long kept = __ballot(act);
        while (true) {
            bool alive = act && ((colmask & kept) == 0ull);
            unsigned long long k2m = __ballot(alive);
            if (k2m == kept) break;
            kept = k2m;
        }
        kept0 = kept;
    }
    // ---- chunk 1 (members 64..cnt-1): rare ----
    if (cnt > 64) {
        int m = 64 + l;
        bool act = (m < cnt);
        float4 a = mbox[act ? m : 0];
        float aarea = (a.z - a.x) * (a.w - a.y);
        bool presup = false;
        for (int t = 0; t < 64; ++t) {
            if ((kept0 >> t) & 1ull) {
                if (act && iou_gt_thr(a, aarea, mbox[t])) presup = true;
            }
        }
        unsigned long long colmask = 0ull;
        for (int t = 64; t < cnt; ++t) {
            float4 tb = mbox[t];
            if ((t - 64) < l && act && iou_gt_thr(a, aarea, tb)) colmask |= (1ull << (t - 64));
        }
        bool pre = act && !presup;
        unsigned long long kept = __ballot(pre);
        while (true) {
            bool alive = pre && ((colmask & kept) == 0ull);
            unsigned long long k2m = __ballot(alive);
            if (k2m == kept) break;
            kept = k2m;
        }
        kept1 = kept;
    }

    // ---- fixed-slot write (disjoint per block; kernel boundary = sync) ----
    int nk0 = __popcll(kept0), nk1 = __popcll(kept1);
    unsigned long long* slot = klist + ((size_t)b * NCLS + cidx) * MCLS;
    if ((kept0 >> l) & 1ull)
        slot[__popcll(kept0 & ((1ull << l) - 1ull))] = mk[l];
    if (cnt > 64 && ((kept1 >> l) & 1ull))
        slot[nk0 + __popcll(kept1 & ((1ull << l) - 1ull))] = mk[64 + l];
    if (l == 0) kslot[b * NCLS + cidx] = nk0 + nk1;
}

// ---- kC: 1 block per batch x 512 threads. Wide staging (R11-validated) +
// histogram threshold (R10-validated) + candidate rank-count. Every phase
// bounded: stage ~20 coalesced iters, hist ~4 iters, threshold 4 scan steps,
// rank ~53 uniform pair-reads over ~106 candidates. ----
__global__ void __launch_bounds__(512) kC_emit(
        const int* __restrict__ kslot,
        const unsigned long long* __restrict__ klist,
        const float* __restrict__ boxes,
        const int* __restrict__ cls,
        float* __restrict__ out) {
    const int b = blockIdx.x;
    const int tid = threadIdx.x;
    const int wv = tid >> 6;
    const int l = tid & 63;

    __shared__ unsigned long long keys[KCAP];        // 16 KB
    __shared__ ulonglong2 cand2[256];                //  4 KB
    __shared__ int hist[256];
    __shared__ int sbase[NCLS], scount[NCLS];
    __shared__ int Tsh, tbsh, candn;
    unsigned long long* cand = (unsigned long long*)cand2;

    if (tid < 256) hist[tid] = 0;
    if (tid == 0) candn = 0;

    // wave 0: 80 slot counts -> exclusive prefix (validated)
    if (wv == 0) {
        const int* ks = kslot + b * NCLS;
        int ns0 = ks[l];
        int ns1 = (l < NCLS - 64) ? ks[64 + l] : 0;
        int incA = ns0, incB = ns1;
        #pragma unroll
        for (int off = 1; off < 64; off <<= 1) {
            int oa = __shfl_up(incA, off);
            int ob = __shfl_up(incB, off);
            if (l >= off) { incA += oa; incB += ob; }
        }
        int total0 = __shfl(incA, 63);
        int T = total0 + __shfl(incB, 63);
        sbase[l] = incA - ns0;
        scount[l] = ns0;
        if (l < NCLS - 64) { sbase[64 + l] = total0 + incB - ns1; scount[64 + l] = ns1; }
        if (l == 0) Tsh = (T > KCAP) ? KCAP : T;
    }
    __syncthreads();
    const int T = Tsh;
    if (T == 0) return;                              // uniform; out pre-zeroed

    // stage: all 80*128 entries, coalesced unconditional loads, predicated
    // LDS scatter (R11-validated; no serial per-slot loop)
    const unsigned long long* kbase = klist + (size_t)b * NCLS * MCLS;
    for (int e = tid; e < NCLS * MCLS; e += 512) {
        unsigned long long v = kbase[e];
        int s = e >> 7, j = e & (MCLS - 1);
        if (j < scount[s]) keys[sbase[s] + j] = v;
    }
    __syncthreads();

    // histogram on score bucket. Kept scores in [0.7,1) -> exponent 126 fixed
    // -> top-8 mantissa bits monotone: bucket = (key >> 47) & 0xFF.
    for (int t = tid; t < T; t += 512)
        atomicAdd(&hist[(int)((keys[t] >> 47) & 0xFF)], 1);
    __syncthreads();

    // wave 0: threshold bucket tb (smallest b' with count(buckets >= b') >= 100)
    if (wv == 0) {
        int cum = 0, tb = 0, done = 0;
        for (int chunk = 3; chunk >= 0 && !done; --chunk) {
            int bkt = chunk * 64 + (63 - l);         // lane 0 = highest bucket
            int s = hist[bkt];
            #pragma unroll
            for (int off = 1; off < 64; off <<= 1) {
                int o = __shfl_up(s, off);
                if (l >= off) s += o;
            }
            int chunktot = __shfl(s, 63);
            if (cum + chunktot >= MAXI) {
                unsigned long long m = __ballot(cum + s >= MAXI);
                int lane = __ffsll((long long)m) - 1;
                tb = chunk * 64 + (63 - lane);
                done = 1;
            } else {
                cum += chunktot;
            }
        }
        if (l == 0) tbsh = done ? tb : 0;            // T<100 -> all buckets
    }
    __syncthreads();
    const int tb = tbsh;

    // compact candidates (bucket >= tb); non-candidates have strictly smaller
    // keys, so rank among candidates == global rank. (R10-validated pattern)
    for (int t = tid; t < ((T + 511) & ~511); t += 512) {
        bool pr = (t < T) && ((int)((keys[t] >> 47) & 0xFF) >= tb);
        unsigned long long m = __ballot(pr);
        int nb = __popcll(m);
        int basew = 0;
        if (l == 0 && nb) basew = atomicAdd(&candn, nb);
        basew = __shfl(basew, 0);
        if (pr) {
            int pos = basew + __popcll(m & ((1ull << l) - 1ull));
            if (pos < 512) cand[pos] = keys[t];
        }
    }
    __syncthreads();
    const int nc = candn;
    if (tid == 0 && nc < 512) cand[nc] = 0ull;       // pad for odd-nc pair read
    __syncthreads();

    if (nc <= 512) {
        // rank-count among candidates (pair reads; ~53 iters for nc~106)
        const int np = (nc + 1) >> 1;
        for (int s = tid; s < nc; s += 512) {
            unsigned long long myk = cand[s];
            int r = 0;
            for (int t = 0; t < np; ++t) {
                ulonglong2 kv = cand2[t];
                r += (int)(kv.x > myk);
                r += (int)(kv.y > myk);              // pad 0 never counts
            }
            if (r < MAXI) {
                int i = (int)(~(unsigned int)myk);
                float4 bx = ((const float4*)boxes)[(size_t)b * NN + i];
                float* o = out + ((size_t)b * MAXI + r) * 6;
                o[0] = bx.x; o[1] = bx.y; o[2] = bx.z; o[3] = bx.w;
                o[4] = (float)cls[(size_t)b * NN + i];
                o[5] = __uint_as_float((unsigned int)(myk >> 32));
            }
        }
    } else {
        // pathological fallback: full rank over all kept keys
        for (int s = tid; s < T; s += 512) {
            unsigned long long myk = keys[s];
            int r = 0;
            for (int t = 0; t < T; ++t) r += (int)(keys[t] > myk);
            if (r < MAXI) {
                int i = (int)(~(unsigned int)myk);
                float4 bx = ((const float4*)boxes)[(size_t)b * NN + i];
                float* o = out + ((size_t)b * MAXI + r) * 6;
                o[0] = bx.x; o[1] = bx.y; o[2] = bx.z; o[3] = bx.w;
                o[4] = (float)cls[(size_t)b * NN + i];
                o[5] = __uint_as_float((unsigned int)(myk >> 32));
            }
        }
    }
}

extern "C" void kernel_launch(void* const* d_in, const int* in_sizes, int n_in,
                              void* d_out, int out_size, void* d_ws, size_t ws_size,
                              hipStream_t stream) {
    const float* rois   = (const float*)d_in[0];
    const float* probs  = (const float*)d_in[1];
    const float* deltas = (const float*)d_in[2];
    float* outp = (float*)d_out;

    char* ws = (char*)d_ws;
    float* boxes = (float*)(ws + 0);
    float* sc    = (float*)(ws + 256000);
    int*   cls   = (int*)  (ws + 320000);
    int*   kslot = (int*)  (ws + 384000);
    unsigned long long* klist = (unsigned long long*)(ws + 386624);

    {
        int blocks = (BB * NN * 64) / 256;   // one wave per ROI, exact
        kA_refine<<<blocks, 256, 0, stream>>>(rois, probs, deltas, boxes, sc, cls, outp);
    }
    {
        kB_nms<<<BB * NCLS, 256, 0, stream>>>(boxes, sc, cls, kslot, klist);
    }
    {
        kC_emit<<<BB, 512, 0, stream>>>(kslot, klist, boxes, cls, outp);
    }
}